// Round 4
// baseline (2453.609 us; speedup 1.0000x reference)
//
#include <hip/hip_runtime.h>

// LightGCN propagation: 3 sparse layers over a fixed bipartite graph.
// R4: (a) revert CSR build to direct counting-sort scatter (R3's two-pass
// multisplit was 90us SLOWER: concurrent grid execution defeats bucket-level
// write locality and staging added 240MB traffic); (b) restructure layers to
// 16 lanes x float4 per row (4 rows/wave): one gather instruction serves 4
// edges -> ~4x fewer VALU/VMEM instructions per edge (R3 was VALU-bound at
// 61% with 1 edge per wave-wide instruction).

#define EMB 64

__global__ void hist_kernel(const int* __restrict__ rows, int* __restrict__ cnt, int nnz) {
    int i = blockIdx.x * blockDim.x + threadIdx.x;
    if (i < nnz) atomicAdd(&cnt[rows[i]], 1);
}

// ---- 3-kernel exclusive scan over M=N+1 counts (2048 elems / block) ----
__global__ void scan1(const int* __restrict__ cnt, int* __restrict__ bsum, int M) {
    __shared__ int s[256];
    int tid  = threadIdx.x;
    int base = blockIdx.x * 2048 + tid * 8;
    int t = 0;
#pragma unroll
    for (int j = 0; j < 8; ++j) { int i = base + j; if (i < M) t += cnt[i]; }
    s[tid] = t; __syncthreads();
    for (int off = 128; off > 0; off >>= 1) {
        if (tid < off) s[tid] += s[tid + off];
        __syncthreads();
    }
    if (tid == 0) bsum[blockIdx.x] = s[0];
}

// single block; requires nb <= 256 (here nb = ceil(300002/2048) = 147)
__global__ void scan2(int* bsum, int nb) {
    __shared__ int s[256];
    int tid = threadIdx.x;
    int x = (tid < nb) ? bsum[tid] : 0;
    int orig = x;
    s[tid] = x; __syncthreads();
    for (int off = 1; off < 256; off <<= 1) {
        int y = (tid >= off) ? s[tid - off] : 0;
        __syncthreads();
        x += y; s[tid] = x; __syncthreads();
    }
    if (tid < nb) bsum[tid] = x - orig;   // exclusive
}

__global__ void scan3(const int* __restrict__ cnt, const int* __restrict__ bsum,
                      int* __restrict__ row_ptr, int* __restrict__ cursor, int M) {
    __shared__ int s[256];
    int tid  = threadIdx.x;
    int base = blockIdx.x * 2048 + tid * 8;
    int v[8]; int t = 0;
#pragma unroll
    for (int j = 0; j < 8; ++j) { int i = base + j; v[j] = (i < M) ? cnt[i] : 0; t += v[j]; }
    int x = t;
    s[tid] = x; __syncthreads();
    for (int off = 1; off < 256; off <<= 1) {
        int y = (tid >= off) ? s[tid - off] : 0;
        __syncthreads();
        x += y; s[tid] = x; __syncthreads();
    }
    int run = bsum[blockIdx.x] + (x - t);   // exclusive prefix for this thread
#pragma unroll
    for (int j = 0; j < 8; ++j) {
        int i = base + j;
        if (i < M) {
            row_ptr[i] = run;
            if (i < M - 1) cursor[i] = run;  // cursor has N entries
        }
        run += v[j];
    }
}

// counting-sort scatter: edge e -> slot in its row's CSR segment.
// nt store hint: random 8B writes have no reuse; don't pollute L2.
__global__ void scatter_kernel(const int* __restrict__ rows, const int* __restrict__ cols,
                               const float* __restrict__ vals, int* __restrict__ cursor,
                               long long* __restrict__ edges, int nnz) {
    int i = blockIdx.x * blockDim.x + threadIdx.x;
    if (i >= nnz) return;
    int r = rows[i];
    int p = atomicAdd(&cursor[r], 1);
    long long packed = ((long long)__float_as_int(vals[i]) << 32) | (unsigned)cols[i];
    __builtin_nontemporal_store(packed, &edges[p]);
}

__device__ __forceinline__ float4 fma4(float s, float4 g, float4 a) {
    a.x = fmaf(s, g.x, a.x); a.y = fmaf(s, g.y, a.y);
    a.z = fmaf(s, g.z, a.z); a.w = fmaf(s, g.w, a.w);
    return a;
}

__device__ __forceinline__ const float4* colbase(int c, const float4* ue, const float4* ie, int nu) {
    return (c < nu) ? (ue + (size_t)c * 16) : (ie + ((size_t)c - nu) * 16);
}

// 16 lanes per row, float4 per lane (16*16B = 64 floats = EMB). 4 rows/wave.
// Edge loads are group-uniform (16-way broadcast, 4 distinct addrs/wave);
// one gather instruction moves 1KB = 4 edges' worth of embedding data.
// MODE 0: first layer (reads ue/ie directly, inits acc = e0 + sum)
// MODE 1: middle layer (acc += sum)
// MODE 2: last layer   (acc = (acc + sum) * 0.25, no embout write)
template<int MODE>
__global__ __launch_bounds__(256) void layer_kernel(
    const int* __restrict__ row_ptr, const int2* __restrict__ edges,
    const float4* __restrict__ embin, const float4* __restrict__ ue4,
    const float4* __restrict__ ie4, float4* __restrict__ embout,
    float4* __restrict__ acc, int N, int nu)
{
    int row = (int)((blockIdx.x * blockDim.x + threadIdx.x) >> 4);
    int sub = threadIdx.x & 15;
    if (row >= N) return;
    int s = row_ptr[row], e = row_ptr[row + 1];
    float4 a0 = {0,0,0,0}, a1 = {0,0,0,0}, a2 = {0,0,0,0}, a3 = {0,0,0,0};
    int i = s;
    for (; i + 8 <= e; i += 8) {
        int2 c0 = edges[i+0], c1 = edges[i+1], c2 = edges[i+2], c3 = edges[i+3];
        int2 c4 = edges[i+4], c5 = edges[i+5], c6 = edges[i+6], c7 = edges[i+7];
        float4 g0, g1, g2, g3, g4, g5, g6, g7;
        if (MODE == 0) {
            g0 = colbase(c0.x, ue4, ie4, nu)[sub];
            g1 = colbase(c1.x, ue4, ie4, nu)[sub];
            g2 = colbase(c2.x, ue4, ie4, nu)[sub];
            g3 = colbase(c3.x, ue4, ie4, nu)[sub];
            g4 = colbase(c4.x, ue4, ie4, nu)[sub];
            g5 = colbase(c5.x, ue4, ie4, nu)[sub];
            g6 = colbase(c6.x, ue4, ie4, nu)[sub];
            g7 = colbase(c7.x, ue4, ie4, nu)[sub];
        } else {
            g0 = embin[(size_t)c0.x * 16 + sub];
            g1 = embin[(size_t)c1.x * 16 + sub];
            g2 = embin[(size_t)c2.x * 16 + sub];
            g3 = embin[(size_t)c3.x * 16 + sub];
            g4 = embin[(size_t)c4.x * 16 + sub];
            g5 = embin[(size_t)c5.x * 16 + sub];
            g6 = embin[(size_t)c6.x * 16 + sub];
            g7 = embin[(size_t)c7.x * 16 + sub];
        }
        a0 = fma4(__int_as_float(c0.y), g0, a0);
        a1 = fma4(__int_as_float(c1.y), g1, a1);
        a2 = fma4(__int_as_float(c2.y), g2, a2);
        a3 = fma4(__int_as_float(c3.y), g3, a3);
        a0 = fma4(__int_as_float(c4.y), g4, a0);
        a1 = fma4(__int_as_float(c5.y), g5, a1);
        a2 = fma4(__int_as_float(c6.y), g6, a2);
        a3 = fma4(__int_as_float(c7.y), g7, a3);
    }
    for (; i < e; ++i) {
        int2 cv = edges[i];
        float4 g = (MODE == 0) ? colbase(cv.x, ue4, ie4, nu)[sub]
                               : embin[(size_t)cv.x * 16 + sub];
        a0 = fma4(__int_as_float(cv.y), g, a0);
    }
    float4 sum;
    sum.x = (a0.x + a1.x) + (a2.x + a3.x);
    sum.y = (a0.y + a1.y) + (a2.y + a3.y);
    sum.z = (a0.z + a1.z) + (a2.z + a3.z);
    sum.w = (a0.w + a1.w) + (a2.w + a3.w);
    size_t idx = (size_t)row * 16 + sub;
    if (MODE != 2) embout[idx] = sum;
    if (MODE == 0) {
        float4 b = (row < nu) ? ue4[idx] : ie4[idx - (size_t)nu * 16];
        sum.x += b.x; sum.y += b.y; sum.z += b.z; sum.w += b.w;
        acc[idx] = sum;
    } else if (MODE == 1) {
        float4 t = acc[idx];
        t.x += sum.x; t.y += sum.y; t.z += sum.z; t.w += sum.w;
        acc[idx] = t;
    } else {
        float4 t = acc[idx];
        t.x = (t.x + sum.x) * 0.25f; t.y = (t.y + sum.y) * 0.25f;
        t.z = (t.z + sum.z) * 0.25f; t.w = (t.w + sum.w) * 0.25f;
        acc[idx] = t;
    }
}

extern "C" void kernel_launch(void* const* d_in, const int* in_sizes, int n_in,
                              void* d_out, int out_size, void* d_ws, size_t ws_size,
                              hipStream_t stream) {
    const float* ue   = (const float*)d_in[0];
    const float* ie   = (const float*)d_in[1];
    const float* vals = (const float*)d_in[2];
    const int*   rows = (const int*)d_in[3];
    const int*   cols = (const int*)d_in[4];

    int nu  = in_sizes[0] / EMB;
    int ni  = in_sizes[1] / EMB;
    int N   = nu + ni;
    int nnz = in_sizes[2];
    int M   = N + 1;

    // workspace carve-out (256B aligned)
    char*  w   = (char*)d_ws;
    size_t off = 0;
    auto alloc = [&](size_t bytes) -> void* {
        void* p = w + off;
        off = (off + bytes + 255) & ~(size_t)255;
        return p;
    };
    float* embA    = (float*)alloc((size_t)N * EMB * sizeof(float));
    float* embB    = (float*)alloc((size_t)N * EMB * sizeof(float));
    int2*  edges   = (int2*) alloc((size_t)nnz * sizeof(int2));
    int*   cnt     = (int*)  alloc((size_t)M * sizeof(int));
    int*   row_ptr = (int*)  alloc((size_t)M * sizeof(int));
    int*   cursor  = (int*)  alloc((size_t)N * sizeof(int));
    int*   bsum    = (int*)  alloc(1024 * sizeof(int));
    float* acc     = (float*)d_out;   // accumulator lives in the output buffer

    hipMemsetAsync(cnt, 0, (size_t)M * sizeof(int), stream);

    hist_kernel<<<(nnz + 255) / 256, 256, 0, stream>>>(rows, cnt, nnz);

    int nsb = (M + 2047) / 2048;
    scan1<<<nsb, 256, 0, stream>>>(cnt, bsum, M);
    scan2<<<1,   256, 0, stream>>>(bsum, nsb);
    scan3<<<nsb, 256, 0, stream>>>(cnt, bsum, row_ptr, cursor, M);

    scatter_kernel<<<(nnz + 255) / 256, 256, 0, stream>>>(rows, cols, vals, cursor,
                                                          (long long*)edges, nnz);

    int lgrid = (N + 15) / 16;   // 16 rows per 256-thread block (16 lanes/row)
    layer_kernel<0><<<lgrid, 256, 0, stream>>>(row_ptr, edges, nullptr,
                                               (const float4*)ue, (const float4*)ie,
                                               (float4*)embA, (float4*)acc, N, nu);
    layer_kernel<1><<<lgrid, 256, 0, stream>>>(row_ptr, edges, (const float4*)embA,
                                               (const float4*)ue, (const float4*)ie,
                                               (float4*)embB, (float4*)acc, N, nu);
    layer_kernel<2><<<lgrid, 256, 0, stream>>>(row_ptr, edges, (const float4*)embB,
                                               (const float4*)ue, (const float4*)ie,
                                               nullptr, (float4*)acc, N, nu);
}